// Round 8
// baseline (25.506 us; speedup 1.0000x reference)
//
#include <hip/hip_runtime.h>
#include <hip/hip_bf16.h>

#define BATCH 8
#define SEQ   4096
#define DEG   16
#define FD    128
#define NTOT  (BATCH * SEQ)
#define ALPHA 0.2f
#define LDS_WK 132   // 128 bf16 + 4 pad per n-row (row stride 264 B)

typedef __attribute__((ext_vector_type(8))) short short8v;   // 8 bf16 (4 VGPRs)
typedef __attribute__((ext_vector_type(4))) short short4v;   // 4 bf16 (2 VGPRs)
typedef __attribute__((ext_vector_type(4))) float float4v;   // MFMA acc
typedef __attribute__((ext_vector_type(4))) float f32x4;
typedef __attribute__((ext_vector_type(2))) float f32x2;
typedef __attribute__((ext_vector_type(4))) unsigned int u32x4;

__device__ __forceinline__ unsigned short f2bf(float f) {
    unsigned int u = __float_as_uint(f);
    u += 0x7fffu + ((u >> 16) & 1u);   // round-to-nearest-even
    return (unsigned short)(u >> 16);
}

// Kernel A (unchanged, proven): transposed-product MFMA h^T = (xW)^T,
// fused s1/s2 dots, wide dwordx2 hb stores.
__global__ __launch_bounds__(256) void gat_proj(
    const float* __restrict__ x, const float* __restrict__ W,
    const float* __restrict__ avec, unsigned short* __restrict__ hb,
    float2* __restrict__ s12)
{
    __shared__ unsigned short Wt[128 * LDS_WK];   // W transposed: Wt[n][k], bf16

    const int t = threadIdx.x;
    const int bid = blockIdx.x;
    const int xcd = bid & 7, blk = bid >> 3;            // batch == XCD
    const long long rowBase = (long long)xcd * SEQ + (long long)blk * 64;

    // stage W -> LDS transposed (coalesced: each half-wave reads a 512-B row)
    {
        const int q = t & 31;                 // n-quad: n = 4q..4q+3
        const int kh = t >> 5;                // 0..7
        #pragma unroll
        for (int j = 0; j < 8; ++j) {
            const int kp = kh + 8 * j;        // k-pair, k = 2kp, 2kp+1
            const f32x4 w0 = *reinterpret_cast<const f32x4*>(&W[(2 * kp) * FD + 4 * q]);
            const f32x4 w1 = *reinterpret_cast<const f32x4*>(&W[(2 * kp + 1) * FD + 4 * q]);
            #pragma unroll
            for (int e2 = 0; e2 < 4; ++e2) {
                const unsigned int pk = (unsigned int)f2bf(w0[e2])
                                      | ((unsigned int)f2bf(w1[e2]) << 16);
                *reinterpret_cast<unsigned int*>(&Wt[(4 * q + e2) * LDS_WK + 2 * kp]) = pk;
            }
        }
    }

    // x rows global -> registers -> bf16 frags (B operand)
    const int lane = t & 63, wv = t >> 6;
    const int g = lane >> 4, mrow = lane & 15;
    const long long node = rowBase + wv * 16 + mrow;    // this lane's node
    short8v xfrag[4];
    {
        const float* xr = x + node * FD + 4 * g;
        #pragma unroll
        for (int kb = 0; kb < 4; ++kb) {
            const f32x4 x0 = __builtin_nontemporal_load(
                reinterpret_cast<const f32x4*>(xr + 32 * kb));
            const f32x4 x1 = __builtin_nontemporal_load(
                reinterpret_cast<const f32x4*>(xr + 32 * kb + 16));
            short8v f;
            f[0] = (short)f2bf(x0[0]); f[1] = (short)f2bf(x0[1]);
            f[2] = (short)f2bf(x0[2]); f[3] = (short)f2bf(x0[3]);
            f[4] = (short)f2bf(x1[0]); f[5] = (short)f2bf(x1[1]);
            f[6] = (short)f2bf(x1[2]); f[7] = (short)f2bf(x1[3]);
            xfrag[kb] = f;
        }
    }
    __syncthreads();

    // MFMA main: 8 n-tiles x 4 k-steps, D = Wt-tile * x-tile (transposed product)
    float4v acc[8];
    #pragma unroll
    for (int tn = 0; tn < 8; ++tn) { acc[tn][0] = 0.f; acc[tn][1] = 0.f; acc[tn][2] = 0.f; acc[tn][3] = 0.f; }

    #pragma unroll
    for (int tn = 0; tn < 8; ++tn) {
        const int nbase = (16 * tn + mrow) * LDS_WK + 4 * g;
        #pragma unroll
        for (int kb = 0; kb < 4; ++kb) {
            const short4v lo = *reinterpret_cast<const short4v*>(&Wt[nbase + 32 * kb]);
            const short4v hi = *reinterpret_cast<const short4v*>(&Wt[nbase + 32 * kb + 16]);
            short8v wf;
            wf[0] = lo[0]; wf[1] = lo[1]; wf[2] = lo[2]; wf[3] = lo[3];
            wf[4] = hi[0]; wf[5] = hi[1]; wf[6] = hi[2]; wf[7] = hi[3];
            acc[tn] = __builtin_amdgcn_mfma_f32_16x16x32_bf16(wf, xfrag[kb], acc[tn], 0, 0, 0);
        }
    }

    // epilogue: lane owns node `node`, h cols 16tn+4g+0..3 per tn
    float s1p = 0.f, s2p = 0.f;
    #pragma unroll
    for (int tn = 0; tn < 8; ++tn) {
        const int col = 16 * tn + 4 * g;
        const unsigned int u0 = (unsigned int)f2bf(acc[tn][0])
                              | ((unsigned int)f2bf(acc[tn][1]) << 16);
        const unsigned int u1 = (unsigned int)f2bf(acc[tn][2])
                              | ((unsigned int)f2bf(acc[tn][3]) << 16);
        *reinterpret_cast<uint2*>(&hb[node * FD + col]) = make_uint2(u0, u1);
        const f32x4 a1 = *reinterpret_cast<const f32x4*>(&avec[col]);
        const f32x4 a2 = *reinterpret_cast<const f32x4*>(&avec[FD + col]);
        #pragma unroll
        for (int r = 0; r < 4; ++r) {
            s1p = fmaf(acc[tn][r], a1[r], s1p);
            s2p = fmaf(acc[tn][r], a2[r], s2p);
        }
    }
    s1p += __shfl_xor(s1p, 16, 64);  s2p += __shfl_xor(s2p, 16, 64);
    s1p += __shfl_xor(s1p, 32, 64);  s2p += __shfl_xor(s2p, 32, 64);
    if (lane < 16)
        s12[rowBase + wv * 16 + lane] = make_float2(s1p, s2p);
}

// Kernel B v3: minimize VMEM INSTRUCTIONS (TA-throughput-bound).
// 4 nodes/wave. Softmax phase: lane 16j+d owns edge (j,d) -- 1 coalesced adj
// load + 1 s12 gather + 1 exp + 4 shfl_xor. Gather phase: lane (g,c) reads
// 16 B of row nb[j][g+4i] via dwordx4 (1 instr = 4 full rows; 16 instrs
// replace 64). Row idx + weight redistributed via ds_bpermute (LDS pipe,
// which is idle). xor16/32 reduce; 4 predicated 512-B dwordx4 stores.
// Budget: 22 vmem instr/wave vs 70 in v2.
__global__ __launch_bounds__(256) void gat_aggr(
    const int* __restrict__ adj, const unsigned short* __restrict__ hb,
    const float2* __restrict__ s12, float* __restrict__ out)
{
    const int t = threadIdx.x;
    const int lane = t & 63;
    const int wv_u = __builtin_amdgcn_readfirstlane(t) >> 6;  // uniform wave id
    const int bid = blockIdx.x;
    const int xcd = bid & 7, blk = bid >> 3;    // 2048 blocks: blk = 0..255
    const int bBase = xcd * SEQ;                // batch == XCD
    const int nodeLoc0 = blk * 16 + wv_u * 4;   // batch-local first node of wave

    // one coalesced 256-B load: adj rows of 4 consecutive nodes
    const int a_l = adj[((long long)(bBase + nodeLoc0)) * DEG + lane];

    // lane-parallel e: lane = 16j+d. s2 of neighbor 0 comes from lane 16j.
    const float2 sv = s12[bBase + a_l];                 // 8-B gather (1 instr)
    const float s2n0 = __shfl(sv.y, lane & 48, 64);
    float ev = sv.x + s2n0;
    ev = ev > 0.f ? ev : ALPHA * ev;
    float p = __expf(ev);          // no max-sub: |e| small, fp32 safe (validated)
    float sum = p;
    #pragma unroll
    for (int mo = 1; mo < 16; mo <<= 1) sum += __shfl_xor(sum, mo, 64);
    p *= 1.f / sum;                // lane 16j+d holds normalized attn p_{j,d}

    // gather-aggregate, dwordx4: lane (g = lane>>4, c = lane&15) covers
    // bytes 16c..16c+15 (feats 8c..8c+7) of neighbor rows d = g+4i.
    const int g = lane >> 4, c = lane & 15;
    #pragma unroll
    for (int j = 0; j < 4; ++j) {
        float acc[8] = {0.f, 0.f, 0.f, 0.f, 0.f, 0.f, 0.f, 0.f};
        #pragma unroll
        for (int i = 0; i < 4; ++i) {
            const int src = 16 * j + g + 4 * i;          // edge slot (j, d=g+4i)
            const int row = __shfl(a_l, src, 64);        // bpermute (LDS pipe)
            const float pw = __shfl(p, src, 64);         // bpermute (LDS pipe)
            const u32x4 u = *reinterpret_cast<const u32x4*>(
                hb + (((long long)(bBase + row)) << 7) + c * 8);
            #pragma unroll
            for (int k = 0; k < 4; ++k) {
                acc[2 * k]     = fmaf(pw, __uint_as_float(u[k] << 16),        acc[2 * k]);
                acc[2 * k + 1] = fmaf(pw, __uint_as_float(u[k] & 0xffff0000u), acc[2 * k + 1]);
            }
        }
        // sum the 4 g-group partials (xor16 + xor32): all lanes get full sums
        #pragma unroll
        for (int k = 0; k < 8; ++k) {
            acc[k] += __shfl_xor(acc[k], 16, 64);
            acc[k] += __shfl_xor(acc[k], 32, 64);
        }
        // lanes g in {0,1} store feats 8c+4g..8c+4g+3 (512 B, one dwordx4)
        if (lane < 32) {
            f32x4 o;
            #pragma unroll
            for (int m = 0; m < 4; ++m) {
                const float v = acc[4 * g + m];
                o[m] = v > 0.f ? v : (__expf(v) - 1.f);   // ELU
            }
            __builtin_nontemporal_store(o, reinterpret_cast<f32x4*>(
                out + ((long long)(bBase + nodeLoc0 + j)) * FD + c * 8 + 4 * g));
        }
    }
}

extern "C" void kernel_launch(void* const* d_in, const int* in_sizes, int n_in,
                              void* d_out, int out_size, void* d_ws, size_t ws_size,
                              hipStream_t stream) {
    const float* x  = (const float*)d_in[0];
    const int* adj  = (const int*)d_in[1];
    const float* W  = (const float*)d_in[2];
    const float* a  = (const float*)d_in[3];
    float* out = (float*)d_out;

    unsigned short* hb = (unsigned short*)d_ws;                          // 8 MB bf16 h
    float2* s12 = (float2*)((char*)d_ws + (size_t)NTOT * FD * 2);        // 256 KB scores

    gat_proj<<<dim3(NTOT / 64), dim3(256), 0, stream>>>(x, W, a, hb, s12);
    gat_aggr<<<dim3(NTOT / 16), dim3(256), 0, stream>>>(adj, hb, s12, out);
}

// Round 9
// 24.618 us; speedup vs baseline: 1.0361x; 1.0361x over previous
//
#include <hip/hip_runtime.h>
#include <hip/hip_bf16.h>

#define BATCH 8
#define SEQ   4096
#define DEG   16
#define FD    128
#define NTOT  (BATCH * SEQ)
#define ALPHA 0.2f
#define LDS_WK 132   // 128 bf16 + 4 pad per n-row (row stride 264 B)

typedef __attribute__((ext_vector_type(8))) short short8v;   // 8 bf16 (4 VGPRs)
typedef __attribute__((ext_vector_type(4))) short short4v;   // 4 bf16 (2 VGPRs)
typedef __attribute__((ext_vector_type(4))) float float4v;   // MFMA acc
typedef __attribute__((ext_vector_type(4))) float f32x4;
typedef __attribute__((ext_vector_type(2))) float f32x2;

__device__ __forceinline__ unsigned short f2bf(float f) {
    unsigned int u = __float_as_uint(f);
    u += 0x7fffu + ((u >> 16) & 1u);   // round-to-nearest-even
    return (unsigned short)(u >> 16);
}

// Kernel A (unchanged, proven): transposed-product MFMA h^T = (xW)^T,
// fused s1/s2 dots, wide dwordx2 hb stores.
__global__ __launch_bounds__(256) void gat_proj(
    const float* __restrict__ x, const float* __restrict__ W,
    const float* __restrict__ avec, unsigned short* __restrict__ hb,
    float2* __restrict__ s12)
{
    __shared__ unsigned short Wt[128 * LDS_WK];   // W transposed: Wt[n][k], bf16

    const int t = threadIdx.x;
    const int bid = blockIdx.x;
    const int xcd = bid & 7, blk = bid >> 3;            // batch == XCD
    const long long rowBase = (long long)xcd * SEQ + (long long)blk * 64;

    // stage W -> LDS transposed (coalesced: each half-wave reads a 512-B row)
    {
        const int q = t & 31;                 // n-quad: n = 4q..4q+3
        const int kh = t >> 5;                // 0..7
        #pragma unroll
        for (int j = 0; j < 8; ++j) {
            const int kp = kh + 8 * j;        // k-pair, k = 2kp, 2kp+1
            const f32x4 w0 = *reinterpret_cast<const f32x4*>(&W[(2 * kp) * FD + 4 * q]);
            const f32x4 w1 = *reinterpret_cast<const f32x4*>(&W[(2 * kp + 1) * FD + 4 * q]);
            #pragma unroll
            for (int e2 = 0; e2 < 4; ++e2) {
                const unsigned int pk = (unsigned int)f2bf(w0[e2])
                                      | ((unsigned int)f2bf(w1[e2]) << 16);
                *reinterpret_cast<unsigned int*>(&Wt[(4 * q + e2) * LDS_WK + 2 * kp]) = pk;
            }
        }
    }

    // x rows global -> registers -> bf16 frags (B operand)
    const int lane = t & 63, wv = t >> 6;
    const int g = lane >> 4, mrow = lane & 15;
    const long long node = rowBase + wv * 16 + mrow;    // this lane's node
    short8v xfrag[4];
    {
        const float* xr = x + node * FD + 4 * g;
        #pragma unroll
        for (int kb = 0; kb < 4; ++kb) {
            const f32x4 x0 = __builtin_nontemporal_load(
                reinterpret_cast<const f32x4*>(xr + 32 * kb));
            const f32x4 x1 = __builtin_nontemporal_load(
                reinterpret_cast<const f32x4*>(xr + 32 * kb + 16));
            short8v f;
            f[0] = (short)f2bf(x0[0]); f[1] = (short)f2bf(x0[1]);
            f[2] = (short)f2bf(x0[2]); f[3] = (short)f2bf(x0[3]);
            f[4] = (short)f2bf(x1[0]); f[5] = (short)f2bf(x1[1]);
            f[6] = (short)f2bf(x1[2]); f[7] = (short)f2bf(x1[3]);
            xfrag[kb] = f;
        }
    }
    __syncthreads();

    // MFMA main: 8 n-tiles x 4 k-steps, D = Wt-tile * x-tile (transposed product)
    float4v acc[8];
    #pragma unroll
    for (int tn = 0; tn < 8; ++tn) { acc[tn][0] = 0.f; acc[tn][1] = 0.f; acc[tn][2] = 0.f; acc[tn][3] = 0.f; }

    #pragma unroll
    for (int tn = 0; tn < 8; ++tn) {
        const int nbase = (16 * tn + mrow) * LDS_WK + 4 * g;
        #pragma unroll
        for (int kb = 0; kb < 4; ++kb) {
            const short4v lo = *reinterpret_cast<const short4v*>(&Wt[nbase + 32 * kb]);
            const short4v hi = *reinterpret_cast<const short4v*>(&Wt[nbase + 32 * kb + 16]);
            short8v wf;
            wf[0] = lo[0]; wf[1] = lo[1]; wf[2] = lo[2]; wf[3] = lo[3];
            wf[4] = hi[0]; wf[5] = hi[1]; wf[6] = hi[2]; wf[7] = hi[3];
            acc[tn] = __builtin_amdgcn_mfma_f32_16x16x32_bf16(wf, xfrag[kb], acc[tn], 0, 0, 0);
        }
    }

    // epilogue: lane owns node `node`, h cols 16tn+4g+0..3 per tn
    float s1p = 0.f, s2p = 0.f;
    #pragma unroll
    for (int tn = 0; tn < 8; ++tn) {
        const int col = 16 * tn + 4 * g;
        const unsigned int u0 = (unsigned int)f2bf(acc[tn][0])
                              | ((unsigned int)f2bf(acc[tn][1]) << 16);
        const unsigned int u1 = (unsigned int)f2bf(acc[tn][2])
                              | ((unsigned int)f2bf(acc[tn][3]) << 16);
        *reinterpret_cast<uint2*>(&hb[node * FD + col]) = make_uint2(u0, u1);
        const f32x4 a1 = *reinterpret_cast<const f32x4*>(&avec[col]);
        const f32x4 a2 = *reinterpret_cast<const f32x4*>(&avec[FD + col]);
        #pragma unroll
        for (int r = 0; r < 4; ++r) {
            s1p = fmaf(acc[tn][r], a1[r], s1p);
            s2p = fmaf(acc[tn][r], a2[r], s2p);
        }
    }
    s1p += __shfl_xor(s1p, 16, 64);  s2p += __shfl_xor(s2p, 16, 64);
    s1p += __shfl_xor(s1p, 32, 64);  s2p += __shfl_xor(s2p, 32, 64);
    if (lane < 16)
        s12[rowBase + wv * 16 + lane] = make_float2(s1p, s2p);
}

// Kernel B v4: cut L2 TRANSACTIONS. The per-batch s12 table (32 KB) is staged
// coalesced into LDS once per block (16 txns/node amortized at 32 nodes/block
// vs 64 random-line txns/node for global s12 gathers). Softmax gathers become
// ds_read_b64. Gather-aggregate phase is round-7's proven readlane form
// (round-8 shfl variant reverted). 1024 blocks x 256 thr = 4 blocks/CU
// co-resident at 32 KB LDS; 8 nodes per wave.
__global__ __launch_bounds__(256) void gat_aggr(
    const int* __restrict__ adj, const unsigned short* __restrict__ hb,
    const float2* __restrict__ s12, float* __restrict__ out)
{
    __shared__ float2 s12t[SEQ];   // 32 KB: whole per-batch score table

    const int t = threadIdx.x;
    const int lane = t & 63;
    const int wv_u = __builtin_amdgcn_readfirstlane(t) >> 6;  // uniform wave id
    const int bid = blockIdx.x;
    const int xcd = bid & 7, blk = bid >> 3;    // 1024 blocks: blk = 0..127
    const int bBase = xcd * SEQ;                // batch == XCD

    // stage s12 table, fully coalesced (16 x 512-B wave-instructions)
    #pragma unroll
    for (int i = 0; i < 16; ++i) {
        const int idx = t + 256 * i;
        s12t[idx] = s12[bBase + idx];
    }
    __syncthreads();

    const int nodeLoc0 = blk * 32 + wv_u * 8;   // batch-local first node of wave

    #pragma unroll
    for (int h = 0; h < 2; ++h) {               // two 4-node halves
        // one coalesced 256-B load: adj rows of 4 consecutive nodes
        const int a_l = adj[((long long)(bBase + nodeLoc0 + 4 * h)) * DEG + lane];

        // lane-parallel e from LDS: lane = 16j+d; s2 of neighbor 0 from lane 16j
        const float2 sv = s12t[a_l];            // ds_read_b64, random (~free)
        const float s2n0 = __shfl(sv.y, lane & 48, 64);
        float ev = sv.x + s2n0;
        ev = ev > 0.f ? ev : ALPHA * ev;
        float p = __expf(ev);      // no max-sub: |e| small, fp32 safe (validated)
        float sum = p;
        #pragma unroll
        for (int mo = 1; mo < 16; mo <<= 1) sum += __shfl_xor(sum, mo, 64);
        p *= 1.f / sum;            // lane 16j+d holds normalized attn p_{j,d}

        // gather-aggregate: 4 independent node chains, idx/weight via readlane
        #pragma unroll
        for (int j = 0; j < 4; ++j) {
            const long long node = (long long)bBase + nodeLoc0 + 4 * h + j;
            float a0 = 0.f, a1 = 0.f;
            #pragma unroll
            for (int d = 0; d < 16; ++d) {
                const int nbjd = __builtin_amdgcn_readlane(a_l, 16 * j + d);  // SGPR
                const float pd = __uint_as_float(
                    __builtin_amdgcn_readlane(__float_as_uint(p), 16 * j + d));
                const unsigned int* rp = reinterpret_cast<const unsigned int*>(
                    hb + (((long long)(bBase + nbjd)) << 7));
                const unsigned int u = rp[lane];   // one 256-B row per instruction
                a0 = fmaf(pd, __uint_as_float(u << 16), a0);
                a1 = fmaf(pd, __uint_as_float(u & 0xffff0000u), a1);
            }
            f32x2 o;
            o[0] = a0 > 0.f ? a0 : (__expf(a0) - 1.f);
            o[1] = a1 > 0.f ? a1 : (__expf(a1) - 1.f);
            __builtin_nontemporal_store(o, reinterpret_cast<f32x2*>(
                out + node * FD + lane * 2));
        }
    }
}

extern "C" void kernel_launch(void* const* d_in, const int* in_sizes, int n_in,
                              void* d_out, int out_size, void* d_ws, size_t ws_size,
                              hipStream_t stream) {
    const float* x  = (const float*)d_in[0];
    const int* adj  = (const int*)d_in[1];
    const float* W  = (const float*)d_in[2];
    const float* a  = (const float*)d_in[3];
    float* out = (float*)d_out;

    unsigned short* hb = (unsigned short*)d_ws;                          // 8 MB bf16 h
    float2* s12 = (float2*)((char*)d_ws + (size_t)NTOT * FD * 2);        // 256 KB scores

    gat_proj<<<dim3(NTOT / 64), dim3(256), 0, stream>>>(x, W, a, hb, s12);
    gat_aggr<<<dim3(NTOT / 32), dim3(256), 0, stream>>>(adj, hb, s12, out);
}